// Round 13
// baseline (122.199 us; speedup 1.0000x reference)
//
#include <hip/hip_runtime.h>
#include <math.h>

#define NB 8192
#define ND 256
#define MARGIN_F 0.3f
#define EPS_F 1e-6f
#define BIAS_F 512.0f          // v = |e_j|^2 + BIAS - 2*dot stays strictly positive
#define NFIN 2048              // finalize grid

typedef __attribute__((ext_vector_type(8))) short bf16x8;
typedef __attribute__((ext_vector_type(4))) float f32x4;

__device__ __forceinline__ unsigned short f2bf(float x) {
    unsigned int u = __float_as_uint(x);
    return (unsigned short)((u + 0x7fffu + ((u >> 16) & 1u)) >> 16);
}

__device__ __forceinline__ void gld16(const void* g, void* l) {
    __builtin_amdgcn_global_load_lds(
        (const __attribute__((address_space(1))) void*)g,
        (__attribute__((address_space(3))) void*)l, 16, 0, 0);
}

// ---- prep: fp32 -> bf16 packed in MFMA-fragment order, + biased sq norms, + key init ----
// Packed layout: subtile = (row>>4)*8 + (k>>5); within: lane = ((k>>3)&3)*16 + (row&15), 8 bf16.
__global__ __launch_bounds__(512) void prep_k(const float* __restrict__ emb,
                                              unsigned short* __restrict__ ehi,
                                              float* __restrict__ sqnb,
                                              unsigned int* __restrict__ pos_key,
                                              unsigned int* __restrict__ neg_key) {
    __shared__ float sm[8][16];
    const int tid = threadIdx.x;
    const int tk = tid >> 6;          // k-tile 0..7
    const int lane = tid & 63;
    const int q = lane >> 4;
    const int lx = lane & 15;
    const int row = blockIdx.x * 16 + lx;
    const int k = tk * 32 + q * 8;

    const float4 v0 = *reinterpret_cast<const float4*>(&emb[(size_t)row * ND + k]);
    const float4 v1 = *reinterpret_cast<const float4*>(&emb[(size_t)row * ND + k + 4]);
    ushort4 h0, h1;
    h0.x = f2bf(v0.x); h0.y = f2bf(v0.y); h0.z = f2bf(v0.z); h0.w = f2bf(v0.w);
    h1.x = f2bf(v1.x); h1.y = f2bf(v1.y); h1.z = f2bf(v1.z); h1.w = f2bf(v1.w);
    *reinterpret_cast<ushort4*>(&ehi[(size_t)blockIdx.x * 4096 + tid * 8])     = h0;
    *reinterpret_cast<ushort4*>(&ehi[(size_t)blockIdx.x * 4096 + tid * 8 + 4]) = h1;

    if (tid >= 32 && tid < 48) pos_key[blockIdx.x * 16 + (tid - 32)] = 0u;
    if (tid >= 48 && tid < 64) neg_key[blockIdx.x * 16 + (tid - 48)] = 0xFFFFFFFFu;

    float s = v0.x * v0.x + v0.y * v0.y + v0.z * v0.z + v0.w * v0.w
            + v1.x * v1.x + v1.y * v1.y + v1.z * v1.z + v1.w * v1.w;
    s += __shfl_xor(s, 16, 64);
    s += __shfl_xor(s, 32, 64);
    if (q == 0) sm[tk][lx] = s;
    __syncthreads();
    if (tid < 16) {
        float t = 0.0f;
#pragma unroll
        for (int wv = 0; wv < 8; ++wv) t += sm[wv][tid];
        sqnb[blockIdx.x * 16 + tid] = t + BIAS_F;
    }
}

// ---- mining epilogue: tree-max reduction, ~7 VALU / element ----
template <bool DIAG>
__device__ __forceinline__ void mine_tile(
        const f32x4 (&acc)[2][4], const float (&sqjc)[4], const int (&lblc)[4],
        const unsigned (&enc)[4], const int* __restrict__ lbl_i_s,
        unsigned (&pmax)[8], unsigned (&nmin)[8],
        int i_base, int jb, int wrow, int q, int lx) {
#pragma unroll
    for (int tr = 0; tr < 2; ++tr) {
#pragma unroll
        for (int reg = 0; reg < 4; ++reg) {
            const int r = tr * 4 + reg;
            const int rowb = wrow + tr * 16 + q * 4 + reg;
            const int lab = lbl_i_s[rowb];
            unsigned pk[4], nk[4];
#pragma unroll
            for (int tc = 0; tc < 4; ++tc) {
                const float v = fmaf(-2.0f, acc[tr][tc][reg], sqjc[tc]);
                const unsigned key = (__float_as_uint(v) & 0xFFFFE000u) | enc[tc];
                const bool same = (lblc[tc] == lab);
                bool pc = same;
                if (DIAG) pc = same && ((jb + tc * 16 + lx) != (i_base + rowb));
                pk[tc] = pc ? key : 0u;
                nk[tc] = same ? 0xFFFFFFFFu : key;
            }
            const unsigned pa = pk[0] >= pk[1] ? pk[0] : pk[1];
            const unsigned pb = pk[2] >= pk[3] ? pk[2] : pk[3];
            const unsigned pm = pa >= pb ? pa : pb;
            pmax[r] = pmax[r] >= pm ? pmax[r] : pm;
            const unsigned na = nk[0] <= nk[1] ? nk[0] : nk[1];
            const unsigned nb = nk[2] <= nk[3] ? nk[2] : nk[3];
            const unsigned nm = na <= nb ? na : nb;
            nmin[r] = nmin[r] <= nm ? nmin[r] : nm;
        }
    }
}

// ---- MFMA pairwise + hardest mining: 128x64 j-steps, B-tile (32 KB) in LDS,
//      A frags transient from global (double-buffered). 3 blocks/CU.
//      grid 512: slice = bid&7 (XCD-affine), i_tile = bid>>3.
//      block 256 = 4 waves; wave w: rows w*32..w*32+31, all 64 cols.
__global__ __launch_bounds__(256, 3) void pair_k(
        const unsigned short* __restrict__ ehi, const float* __restrict__ sqnb,
        const int* __restrict__ labels,
        unsigned int* __restrict__ pos_key, unsigned int* __restrict__ neg_key) {
    __shared__ short Bsh[32 * 512];  // B j-step: 64 cols x 256 k = 16384 shorts = 32 KB
    __shared__ int   lbl_i_s[128];

    const int tid = threadIdx.x;
    const int w = tid >> 6;
    const int lane = tid & 63;
    const int q = lane >> 4;
    const int lx = lane & 15;
    const int bid = blockIdx.x;
    const int slice = bid & 7;
    const int i_base = (bid >> 3) * 128;
    const int wrow = w * 32;
    const int g0 = (i_base >> 4) + w * 2;   // A row-group base for this wave (2 subtiles)

    if (tid < 128) lbl_i_s[tid] = labels[i_base + tid];

    unsigned pmax[8], nmin[8];
#pragma unroll
    for (int r = 0; r < 8; ++r) { pmax[r] = 0u; nmin[r] = 0xFFFFFFFFu; }

#pragma unroll 1
    for (int jt = 0; jt < 16; ++jt) {
        const int jb = slice * 1024 + jt * 64;
        __syncthreads();   // prev j-step's Bsh reads complete
        // stage B j-step: contiguous 32 KB of packed ehi (8 gld16/thread)
        {
            const unsigned short* srcB = ehi + (size_t)(jb >> 4) * 4096;
#pragma unroll
            for (int p = 0; p < 8; ++p)
                gld16(srcB + ((size_t)p * 256 + tid) * 8, Bsh + (p * 256 + tid) * 8);
        }
        // j-step metadata + first A frags issued before the drain barrier
        int lblc[4]; float sqjc[4]; unsigned enc[4];
#pragma unroll
        for (int tc = 0; tc < 4; ++tc) {
            const int jj = jb + tc * 16 + lx;
            lblc[tc] = labels[jj];
            sqjc[tc] = sqnb[jj];
            enc[tc] = 8191u - (unsigned)jj;
        }
        bf16x8 a0[2], a1[2];
#pragma unroll
        for (int tr = 0; tr < 2; ++tr)
            a0[tr] = *(const bf16x8*)&ehi[((size_t)(g0 + tr) * 8 + 0) * 512 + lane * 8];
        __syncthreads();   // gld16 drained; Bsh visible

        f32x4 acc[2][4];
#pragma unroll
        for (int a = 0; a < 2; ++a)
#pragma unroll
            for (int b = 0; b < 4; ++b) acc[a][b] = (f32x4){0.f, 0.f, 0.f, 0.f};

#pragma unroll 1
        for (int kb2 = 0; kb2 < 4; ++kb2) {
            const int kbe = kb2 * 2, kbo = kbe + 1;
#pragma unroll
            for (int tr = 0; tr < 2; ++tr)
                a1[tr] = *(const bf16x8*)&ehi[((size_t)(g0 + tr) * 8 + kbo) * 512 + lane * 8];
            {
                bf16x8 bh[4];
#pragma unroll
                for (int tc = 0; tc < 4; ++tc)
                    bh[tc] = *(const bf16x8*)&Bsh[(tc * 8 + kbe) * 512 + lane * 8];
#pragma unroll
                for (int tr = 0; tr < 2; ++tr)
#pragma unroll
                    for (int tc = 0; tc < 4; ++tc)
                        acc[tr][tc] = __builtin_amdgcn_mfma_f32_16x16x32_bf16(
                            a0[tr], bh[tc], acc[tr][tc], 0, 0, 0);
            }
            const int kbn = (kbe + 2) & 7;
#pragma unroll
            for (int tr = 0; tr < 2; ++tr)
                a0[tr] = *(const bf16x8*)&ehi[((size_t)(g0 + tr) * 8 + kbn) * 512 + lane * 8];
            {
                bf16x8 bh[4];
#pragma unroll
                for (int tc = 0; tc < 4; ++tc)
                    bh[tc] = *(const bf16x8*)&Bsh[(tc * 8 + kbo) * 512 + lane * 8];
#pragma unroll
                for (int tr = 0; tr < 2; ++tr)
#pragma unroll
                    for (int tc = 0; tc < 4; ++tc)
                        acc[tr][tc] = __builtin_amdgcn_mfma_f32_16x16x32_bf16(
                            a1[tr], bh[tc], acc[tr][tc], 0, 0, 0);
            }
        }

        if ((unsigned)(jb - i_base) < 128u)
            mine_tile<true>(acc, sqjc, lblc, enc, lbl_i_s, pmax, nmin, i_base, jb, wrow, q, lx);
        else
            mine_tile<false>(acc, sqjc, lblc, enc, lbl_i_s, pmax, nmin, i_base, jb, wrow, q, lx);
    }

    // once-per-kernel cross-lane reduce (16-lane groups) + spread-address atomics
#pragma unroll
    for (int r = 0; r < 8; ++r) {
        unsigned pm = pmax[r], nm = nmin[r];
#pragma unroll
        for (int mm = 1; mm < 16; mm <<= 1) {
            const unsigned pm2 = __shfl_xor(pm, mm, 64);
            const unsigned nm2 = __shfl_xor(nm, mm, 64);
            pm = pm >= pm2 ? pm : pm2;
            nm = nm <= nm2 ? nm : nm2;
        }
        if (lx == r) {
            const int row = i_base + wrow + (r >> 2) * 16 + q * 4 + (r & 3);
            atomicMax(&pos_key[row], pm);
            atomicMin(&neg_key[row], nm);
        }
    }
}

// ---- finalize: decode keys, exact fp32 gather, hinge, per-block partial stores ----
__global__ __launch_bounds__(256) void final_k(
        const float* __restrict__ emb,
        const unsigned int* __restrict__ pos_key, const unsigned int* __restrict__ neg_key,
        float* __restrict__ pbsum, float* __restrict__ pbcnt) {
    __shared__ float ssum[4], scnt[4];
    const int w = threadIdx.x >> 6;
    const int lane = threadIdx.x & 63;
    const int i = blockIdx.x * 4 + w;

    const unsigned pk = pos_key[i], nk = neg_key[i];
    const int pi = 8191 - (int)(pk & 8191u);
    const int ni = 8191 - (int)(nk & 8191u);
    const bool valid = (pk != 0u) && (nk != 0xFFFFFFFFu);

    const float4 av  = *reinterpret_cast<const float4*>(&emb[(size_t)i  * ND + lane * 4]);
    const float4 pvv = *reinterpret_cast<const float4*>(&emb[(size_t)pi * ND + lane * 4]);
    const float4 nvv = *reinterpret_cast<const float4*>(&emb[(size_t)ni * ND + lane * 4]);
    float sap, san;
    {
        const float d0 = av.x - pvv.x + EPS_F, d1 = av.y - pvv.y + EPS_F;
        const float d2 = av.z - pvv.z + EPS_F, d3 = av.w - pvv.w + EPS_F;
        sap = d0 * d0 + d1 * d1 + d2 * d2 + d3 * d3;
        const float e0 = av.x - nvv.x + EPS_F, e1 = av.y - nvv.y + EPS_F;
        const float e2 = av.z - nvv.z + EPS_F, e3 = av.w - nvv.w + EPS_F;
        san = e0 * e0 + e1 * e1 + e2 * e2 + e3 * e3;
    }
#pragma unroll
    for (int m = 32; m; m >>= 1) {
        sap += __shfl_down(sap, m, 64);
        san += __shfl_down(san, m, 64);
    }
    if (lane == 0) {
        const float per = fmaxf(sqrtf(sap) - sqrtf(san) + MARGIN_F, 0.0f);
        ssum[w] = valid ? per : 0.0f;
        scnt[w] = valid ? 1.0f : 0.0f;
    }
    __syncthreads();
    if (threadIdx.x == 0) {
        pbsum[blockIdx.x] = ssum[0] + ssum[1] + ssum[2] + ssum[3];
        pbcnt[blockIdx.x] = scnt[0] + scnt[1] + scnt[2] + scnt[3];
    }
}

// ---- final mean over 2048 per-block partials ----
__global__ __launch_bounds__(256) void reduce_k(const float* __restrict__ pbsum,
                                                const float* __restrict__ pbcnt,
                                                float* __restrict__ out) {
    __shared__ float fs[4], fc[4];
    const int tid = threadIdx.x;
    float s = 0.0f, c = 0.0f;
#pragma unroll
    for (int r = 0; r < NFIN / 256; ++r) {
        s += pbsum[r * 256 + tid];
        c += pbcnt[r * 256 + tid];
    }
#pragma unroll
    for (int m = 32; m; m >>= 1) { s += __shfl_down(s, m, 64); c += __shfl_down(c, m, 64); }
    const int wv = tid >> 6, lane = tid & 63;
    if (lane == 0) { fs[wv] = s; fc[wv] = c; }
    __syncthreads();
    if (tid == 0) {
        const float S = fs[0] + fs[1] + fs[2] + fs[3];
        const float C = fc[0] + fc[1] + fc[2] + fc[3];
        out[0] = (C > 0.0f) ? (S / fmaxf(C, 1.0f)) : 0.0f;
    }
}

extern "C" void kernel_launch(void* const* d_in, const int* in_sizes, int n_in,
                              void* d_out, int out_size, void* d_ws, size_t ws_size,
                              hipStream_t stream) {
    const float* emb = (const float*)d_in[0];
    const int* labels = (const int*)d_in[1];
    float* out = (float*)d_out;

    char* ws = (char*)d_ws;
    unsigned short* ehi = (unsigned short*)ws;                         // 4 MB packed
    float* sqnb = (float*)(ws + (size_t)NB * ND * 2);                  // 32 KB
    unsigned int* pos_key = (unsigned int*)(sqnb + NB);                // 32 KB
    unsigned int* neg_key = pos_key + NB;                              // 32 KB
    float* pbsum = (float*)(neg_key + NB);                             // 8 KB
    float* pbcnt = pbsum + NFIN;                                       // 8 KB

    hipLaunchKernelGGL(prep_k, dim3(NB / 16), dim3(512), 0, stream,
                       emb, ehi, sqnb, pos_key, neg_key);
    hipLaunchKernelGGL(pair_k, dim3(512), dim3(256), 0, stream,
                       ehi, sqnb, labels, pos_key, neg_key);
    hipLaunchKernelGGL(final_k, dim3(NFIN), dim3(256), 0, stream,
                       emb, pos_key, neg_key, pbsum, pbcnt);
    hipLaunchKernelGGL(reduce_k, dim3(1), dim3(256), 0, stream, pbsum, pbcnt, out);
}

// Round 14
// 115.378 us; speedup vs baseline: 1.0591x; 1.0591x over previous
//
#include <hip/hip_runtime.h>
#include <math.h>

#define NB 8192
#define ND 256
#define MARGIN_F 0.3f
#define EPS_F 1e-6f
#define BIAS_F 512.0f          // v = |e_j|^2 + BIAS - 2*dot stays strictly positive
#define NFIN 2048              // finalize grid

typedef __attribute__((ext_vector_type(8))) short bf16x8;
typedef __attribute__((ext_vector_type(4))) float f32x4;

__device__ __forceinline__ unsigned short f2bf(float x) {
    unsigned int u = __float_as_uint(x);
    return (unsigned short)((u + 0x7fffu + ((u >> 16) & 1u)) >> 16);
}

__device__ __forceinline__ void gld16(const void* g, void* l) {
    __builtin_amdgcn_global_load_lds(
        (const __attribute__((address_space(1))) void*)g,
        (__attribute__((address_space(3))) void*)l, 16, 0, 0);
}

// ---- prep: fp32 -> bf16 packed in MFMA-fragment order, + biased sq norms, + key init ----
// Packed layout: subtile = (row>>4)*8 + (k>>5); within: lane = ((k>>3)&3)*16 + (row&15), 8 bf16.
__global__ __launch_bounds__(512) void prep_k(const float* __restrict__ emb,
                                              unsigned short* __restrict__ ehi,
                                              float* __restrict__ sqnb,
                                              unsigned int* __restrict__ pos_key,
                                              unsigned int* __restrict__ neg_key) {
    __shared__ float sm[8][16];
    const int tid = threadIdx.x;
    const int tk = tid >> 6;          // k-tile 0..7
    const int lane = tid & 63;
    const int q = lane >> 4;
    const int lx = lane & 15;
    const int row = blockIdx.x * 16 + lx;
    const int k = tk * 32 + q * 8;

    const float4 v0 = *reinterpret_cast<const float4*>(&emb[(size_t)row * ND + k]);
    const float4 v1 = *reinterpret_cast<const float4*>(&emb[(size_t)row * ND + k + 4]);
    ushort4 h0, h1;
    h0.x = f2bf(v0.x); h0.y = f2bf(v0.y); h0.z = f2bf(v0.z); h0.w = f2bf(v0.w);
    h1.x = f2bf(v1.x); h1.y = f2bf(v1.y); h1.z = f2bf(v1.z); h1.w = f2bf(v1.w);
    *reinterpret_cast<ushort4*>(&ehi[(size_t)blockIdx.x * 4096 + tid * 8])     = h0;
    *reinterpret_cast<ushort4*>(&ehi[(size_t)blockIdx.x * 4096 + tid * 8 + 4]) = h1;

    if (tid >= 32 && tid < 48) pos_key[blockIdx.x * 16 + (tid - 32)] = 0u;
    if (tid >= 48 && tid < 64) neg_key[blockIdx.x * 16 + (tid - 48)] = 0xFFFFFFFFu;

    float s = v0.x * v0.x + v0.y * v0.y + v0.z * v0.z + v0.w * v0.w
            + v1.x * v1.x + v1.y * v1.y + v1.z * v1.z + v1.w * v1.w;
    s += __shfl_xor(s, 16, 64);
    s += __shfl_xor(s, 32, 64);
    if (q == 0) sm[tk][lx] = s;
    __syncthreads();
    if (tid < 16) {
        float t = 0.0f;
#pragma unroll
        for (int wv = 0; wv < 8; ++wv) t += sm[wv][tid];
        sqnb[blockIdx.x * 16 + tid] = t + BIAS_F;
    }
}

// ---- mining epilogue: tree-max reduction, ~7 VALU / element ----
template <bool DIAG>
__device__ __forceinline__ void mine_tile(
        const f32x4 (&acc)[2][4], const float (&sqjc)[4], const int (&lblc)[4],
        const unsigned (&enc)[4], const int* __restrict__ lbl_i_s,
        unsigned (&pmax)[8], unsigned (&nmin)[8],
        int i_base, int jb, int wrow, int q, int lx) {
#pragma unroll
    for (int tr = 0; tr < 2; ++tr) {
#pragma unroll
        for (int reg = 0; reg < 4; ++reg) {
            const int r = tr * 4 + reg;
            const int rowb = wrow + tr * 16 + q * 4 + reg;
            const int lab = lbl_i_s[rowb];
            unsigned pk[4], nk[4];
#pragma unroll
            for (int tc = 0; tc < 4; ++tc) {
                const float v = fmaf(-2.0f, acc[tr][tc][reg], sqjc[tc]);
                const unsigned key = (__float_as_uint(v) & 0xFFFFE000u) | enc[tc];
                const bool same = (lblc[tc] == lab);
                bool pc = same;
                if (DIAG) pc = same && ((jb + tc * 16 + lx) != (i_base + rowb));
                pk[tc] = pc ? key : 0u;
                nk[tc] = same ? 0xFFFFFFFFu : key;
            }
            const unsigned pa = pk[0] >= pk[1] ? pk[0] : pk[1];
            const unsigned pb = pk[2] >= pk[3] ? pk[2] : pk[3];
            const unsigned pm = pa >= pb ? pa : pb;
            pmax[r] = pmax[r] >= pm ? pmax[r] : pm;
            const unsigned na = nk[0] <= nk[1] ? nk[0] : nk[1];
            const unsigned nb = nk[2] <= nk[3] ? nk[2] : nk[3];
            const unsigned nm = na <= nb ? na : nb;
            nmin[r] = nmin[r] <= nm ? nmin[r] : nm;
        }
    }
}

// ---- MFMA pairwise + hardest mining: 128x64 j-steps, B-step (32 KB) in LDS,
//      A frags transient from global (double-buffered). grid 1024 -> 4 blocks/CU.
//      slice = bid&15 (512 cols), i_tile = bid>>4. block 256 = 4 waves;
//      wave w: rows w*32..w*32+31, all 64 cols.
__global__ __launch_bounds__(256, 4) void pair_k(
        const unsigned short* __restrict__ ehi, const float* __restrict__ sqnb,
        const int* __restrict__ labels,
        unsigned int* __restrict__ pos_key, unsigned int* __restrict__ neg_key) {
    __shared__ short Bsh[32 * 512];  // B j-step: 64 cols x 256 k = 16384 shorts = 32 KB
    __shared__ int   lbl_i_s[128];

    const int tid = threadIdx.x;
    const int w = tid >> 6;
    const int lane = tid & 63;
    const int q = lane >> 4;
    const int lx = lane & 15;
    const int bid = blockIdx.x;
    const int slice = bid & 15;
    const int i_base = (bid >> 4) * 128;
    const int wrow = w * 32;
    const int g0 = (i_base >> 4) + w * 2;   // A row-group base for this wave (2 subtiles)

    if (tid < 128) lbl_i_s[tid] = labels[i_base + tid];

    unsigned pmax[8], nmin[8];
#pragma unroll
    for (int r = 0; r < 8; ++r) { pmax[r] = 0u; nmin[r] = 0xFFFFFFFFu; }

#pragma unroll 1
    for (int jt = 0; jt < 8; ++jt) {
        const int jb = slice * 512 + jt * 64;
        __syncthreads();   // prev j-step's Bsh reads complete
        // stage B j-step: contiguous 32 KB of packed ehi (8 gld16/thread)
        {
            const unsigned short* srcB = ehi + (size_t)(jb >> 4) * 4096;
#pragma unroll
            for (int p = 0; p < 8; ++p)
                gld16(srcB + ((size_t)p * 256 + tid) * 8, Bsh + (p * 256 + tid) * 8);
        }
        // j-step metadata + first A frags issued before the drain barrier
        int lblc[4]; float sqjc[4]; unsigned enc[4];
#pragma unroll
        for (int tc = 0; tc < 4; ++tc) {
            const int jj = jb + tc * 16 + lx;
            lblc[tc] = labels[jj];
            sqjc[tc] = sqnb[jj];
            enc[tc] = 8191u - (unsigned)jj;
        }
        bf16x8 a0[2], a1[2];
#pragma unroll
        for (int tr = 0; tr < 2; ++tr)
            a0[tr] = *(const bf16x8*)&ehi[((size_t)(g0 + tr) * 8 + 0) * 512 + lane * 8];
        __syncthreads();   // gld16 drained; Bsh visible

        f32x4 acc[2][4];
#pragma unroll
        for (int a = 0; a < 2; ++a)
#pragma unroll
            for (int b = 0; b < 4; ++b) acc[a][b] = (f32x4){0.f, 0.f, 0.f, 0.f};

#pragma unroll 1
        for (int kb2 = 0; kb2 < 4; ++kb2) {
            const int kbe = kb2 * 2, kbo = kbe + 1;
#pragma unroll
            for (int tr = 0; tr < 2; ++tr)
                a1[tr] = *(const bf16x8*)&ehi[((size_t)(g0 + tr) * 8 + kbo) * 512 + lane * 8];
            {
                bf16x8 bh[4];
#pragma unroll
                for (int tc = 0; tc < 4; ++tc)
                    bh[tc] = *(const bf16x8*)&Bsh[(tc * 8 + kbe) * 512 + lane * 8];
#pragma unroll
                for (int tr = 0; tr < 2; ++tr)
#pragma unroll
                    for (int tc = 0; tc < 4; ++tc)
                        acc[tr][tc] = __builtin_amdgcn_mfma_f32_16x16x32_bf16(
                            a0[tr], bh[tc], acc[tr][tc], 0, 0, 0);
            }
            const int kbn = (kbe + 2) & 7;
#pragma unroll
            for (int tr = 0; tr < 2; ++tr)
                a0[tr] = *(const bf16x8*)&ehi[((size_t)(g0 + tr) * 8 + kbn) * 512 + lane * 8];
            {
                bf16x8 bh[4];
#pragma unroll
                for (int tc = 0; tc < 4; ++tc)
                    bh[tc] = *(const bf16x8*)&Bsh[(tc * 8 + kbo) * 512 + lane * 8];
#pragma unroll
                for (int tr = 0; tr < 2; ++tr)
#pragma unroll
                    for (int tc = 0; tc < 4; ++tc)
                        acc[tr][tc] = __builtin_amdgcn_mfma_f32_16x16x32_bf16(
                            a1[tr], bh[tc], acc[tr][tc], 0, 0, 0);
            }
        }

        if ((unsigned)(jb - i_base) < 128u)
            mine_tile<true>(acc, sqjc, lblc, enc, lbl_i_s, pmax, nmin, i_base, jb, wrow, q, lx);
        else
            mine_tile<false>(acc, sqjc, lblc, enc, lbl_i_s, pmax, nmin, i_base, jb, wrow, q, lx);
    }

    // once-per-kernel cross-lane reduce (16-lane groups) + spread-address atomics
#pragma unroll
    for (int r = 0; r < 8; ++r) {
        unsigned pm = pmax[r], nm = nmin[r];
#pragma unroll
        for (int mm = 1; mm < 16; mm <<= 1) {
            const unsigned pm2 = __shfl_xor(pm, mm, 64);
            const unsigned nm2 = __shfl_xor(nm, mm, 64);
            pm = pm >= pm2 ? pm : pm2;
            nm = nm <= nm2 ? nm : nm2;
        }
        if (lx == r) {
            const int row = i_base + wrow + (r >> 2) * 16 + q * 4 + (r & 3);
            atomicMax(&pos_key[row], pm);
            atomicMin(&neg_key[row], nm);
        }
    }
}

// ---- finalize: decode keys, exact fp32 gather, hinge, per-block partial stores ----
__global__ __launch_bounds__(256) void final_k(
        const float* __restrict__ emb,
        const unsigned int* __restrict__ pos_key, const unsigned int* __restrict__ neg_key,
        float* __restrict__ pbsum, float* __restrict__ pbcnt) {
    __shared__ float ssum[4], scnt[4];
    const int w = threadIdx.x >> 6;
    const int lane = threadIdx.x & 63;
    const int i = blockIdx.x * 4 + w;

    const unsigned pk = pos_key[i], nk = neg_key[i];
    const int pi = 8191 - (int)(pk & 8191u);
    const int ni = 8191 - (int)(nk & 8191u);
    const bool valid = (pk != 0u) && (nk != 0xFFFFFFFFu);

    const float4 av  = *reinterpret_cast<const float4*>(&emb[(size_t)i  * ND + lane * 4]);
    const float4 pvv = *reinterpret_cast<const float4*>(&emb[(size_t)pi * ND + lane * 4]);
    const float4 nvv = *reinterpret_cast<const float4*>(&emb[(size_t)ni * ND + lane * 4]);
    float sap, san;
    {
        const float d0 = av.x - pvv.x + EPS_F, d1 = av.y - pvv.y + EPS_F;
        const float d2 = av.z - pvv.z + EPS_F, d3 = av.w - pvv.w + EPS_F;
        sap = d0 * d0 + d1 * d1 + d2 * d2 + d3 * d3;
        const float e0 = av.x - nvv.x + EPS_F, e1 = av.y - nvv.y + EPS_F;
        const float e2 = av.z - nvv.z + EPS_F, e3 = av.w - nvv.w + EPS_F;
        san = e0 * e0 + e1 * e1 + e2 * e2 + e3 * e3;
    }
#pragma unroll
    for (int m = 32; m; m >>= 1) {
        sap += __shfl_down(sap, m, 64);
        san += __shfl_down(san, m, 64);
    }
    if (lane == 0) {
        const float per = fmaxf(sqrtf(sap) - sqrtf(san) + MARGIN_F, 0.0f);
        ssum[w] = valid ? per : 0.0f;
        scnt[w] = valid ? 1.0f : 0.0f;
    }
    __syncthreads();
    if (threadIdx.x == 0) {
        pbsum[blockIdx.x] = ssum[0] + ssum[1] + ssum[2] + ssum[3];
        pbcnt[blockIdx.x] = scnt[0] + scnt[1] + scnt[2] + scnt[3];
    }
}

// ---- final mean over 2048 per-block partials ----
__global__ __launch_bounds__(256) void reduce_k(const float* __restrict__ pbsum,
                                                const float* __restrict__ pbcnt,
                                                float* __restrict__ out) {
    __shared__ float fs[4], fc[4];
    const int tid = threadIdx.x;
    float s = 0.0f, c = 0.0f;
#pragma unroll
    for (int r = 0; r < NFIN / 256; ++r) {
        s += pbsum[r * 256 + tid];
        c += pbcnt[r * 256 + tid];
    }
#pragma unroll
    for (int m = 32; m; m >>= 1) { s += __shfl_down(s, m, 64); c += __shfl_down(c, m, 64); }
    const int wv = tid >> 6, lane = tid & 63;
    if (lane == 0) { fs[wv] = s; fc[wv] = c; }
    __syncthreads();
    if (tid == 0) {
        const float S = fs[0] + fs[1] + fs[2] + fs[3];
        const float C = fc[0] + fc[1] + fc[2] + fc[3];
        out[0] = (C > 0.0f) ? (S / fmaxf(C, 1.0f)) : 0.0f;
    }
}

extern "C" void kernel_launch(void* const* d_in, const int* in_sizes, int n_in,
                              void* d_out, int out_size, void* d_ws, size_t ws_size,
                              hipStream_t stream) {
    const float* emb = (const float*)d_in[0];
    const int* labels = (const int*)d_in[1];
    float* out = (float*)d_out;

    char* ws = (char*)d_ws;
    unsigned short* ehi = (unsigned short*)ws;                         // 4 MB packed
    float* sqnb = (float*)(ws + (size_t)NB * ND * 2);                  // 32 KB
    unsigned int* pos_key = (unsigned int*)(sqnb + NB);                // 32 KB
    unsigned int* neg_key = pos_key + NB;                              // 32 KB
    float* pbsum = (float*)(neg_key + NB);                             // 8 KB
    float* pbcnt = pbsum + NFIN;                                       // 8 KB

    hipLaunchKernelGGL(prep_k, dim3(NB / 16), dim3(512), 0, stream,
                       emb, ehi, sqnb, pos_key, neg_key);
    hipLaunchKernelGGL(pair_k, dim3(1024), dim3(256), 0, stream,
                       ehi, sqnb, labels, pos_key, neg_key);
    hipLaunchKernelGGL(final_k, dim3(NFIN), dim3(256), 0, stream,
                       emb, pos_key, neg_key, pbsum, pbcnt);
    hipLaunchKernelGGL(reduce_k, dim3(1), dim3(256), 0, stream, pbsum, pbcnt, out);
}